// Round 1
// baseline (271.745 us; speedup 1.0000x reference)
//
#include <hip/hip_runtime.h>
#include <math.h>

#define NB 8192
#define NG 8
#define NK 1024
#define ND 64
#define GD (NG * ND)          // 512

// ws float-indexed layout:
// [0, 8192)           c2[g][k]
// [8192, 9216)        histogram (unsigned)
// [9216, 9216+256)    per-block commitment partials
#define WS_C2   0
#define WS_HIST 8192
#define WS_PART 9216
#define NBLK    256           // main-kernel block count (32 x 8)

// ---------------- c2 + hist init ----------------
__global__ __launch_bounds__(256) void vq_c2(const float* __restrict__ cb,
                                             float* ws) {
    const int gid = blockIdx.x * 256 + threadIdx.x;   // 0 .. 8191
    const float* c = cb + (size_t)gid * ND;
    float a0 = 0.f, a1 = 0.f, a2 = 0.f, a3 = 0.f;
#pragma unroll
    for (int d = 0; d < ND; d += 4) {
        const float4 v = reinterpret_cast<const float4*>(c)[d >> 2];
        a0 = fmaf(v.x, v.x, a0);
        a1 = fmaf(v.y, v.y, a1);
        a2 = fmaf(v.z, v.z, a2);
        a3 = fmaf(v.w, v.w, a3);
    }
    ws[WS_C2 + gid] = (a0 + a1) + (a2 + a3);
    if (gid < NK) reinterpret_cast<unsigned*>(ws)[WS_HIST + gid] = 0u;
}

// ---------------- main: distances, argmin, gather, outputs ----------------
__global__ __launch_bounds__(256) void vq_main(const float* __restrict__ z,
                                               const float* __restrict__ cb,
                                               float* out, float* ws) {
    const int tid = threadIdx.x;
    const int row = blockIdx.x * 256 + tid;
    const int g   = blockIdx.y;

    const float* zr = z + (size_t)row * GD + (size_t)g * ND;
    float zv[ND];
#pragma unroll
    for (int i = 0; i < ND / 4; ++i) {
        const float4 v = reinterpret_cast<const float4*>(zr)[i];
        zv[4 * i + 0] = v.x; zv[4 * i + 1] = v.y;
        zv[4 * i + 2] = v.z; zv[4 * i + 3] = v.w;
    }
    float z2 = 0.f;
#pragma unroll
    for (int d = 0; d < ND; ++d) z2 += zv[d] * zv[d];

    const float* cg  = cb + (size_t)g * NK * ND;   // group codebook (wave-uniform)
    const float* c2g = ws + WS_C2 + g * NK;

    float best = INFINITY;
    int   bidx = 0;
    for (int k = 0; k < NK; ++k) {
        const float* ck = cg + (size_t)k * ND;     // wave-uniform -> s_load
        float a0 = 0.f, a1 = 0.f, a2 = 0.f, a3 = 0.f;
#pragma unroll
        for (int d = 0; d < ND; d += 4) {
            a0 = fmaf(zv[d + 0], ck[d + 0], a0);
            a1 = fmaf(zv[d + 1], ck[d + 1], a1);
            a2 = fmaf(zv[d + 2], ck[d + 2], a2);
            a3 = fmaf(zv[d + 3], ck[d + 3], a3);
        }
        const float zc   = (a0 + a1) + (a2 + a3);
        const float dist = (z2 + c2g[k]) - 2.0f * zc;   // matches ref formula
        if (dist < best) { best = dist; bidx = k; }     // first-min tie-break
    }

    // gather zq, write quantized = zg + (zq - zg), accumulate commitment
    const float* qk = cg + (size_t)bidx * ND;           // per-lane gather (L2)
    float* orow = out + (size_t)row * GD + (size_t)g * ND;
    float lsum = 0.f;
#pragma unroll
    for (int i = 0; i < ND / 4; ++i) {
        const float4 q = reinterpret_cast<const float4*>(qk)[i];
        const float x0 = zv[4 * i + 0], x1 = zv[4 * i + 1];
        const float x2 = zv[4 * i + 2], x3 = zv[4 * i + 3];
        float4 o;
        o.x = x0 + (q.x - x0);
        o.y = x1 + (q.y - x1);
        o.z = x2 + (q.z - x2);
        o.w = x3 + (q.w - x3);
        reinterpret_cast<float4*>(orow)[i] = o;
        const float d0 = x0 - q.x, d1 = x1 - q.y;
        const float d2 = x2 - q.z, d3 = x3 - q.w;
        lsum += d0 * d0;
        lsum += d1 * d1;
        lsum += d2 * d2;
        lsum += d3 * d3;
    }

    // indices as float
    out[(size_t)NB * GD + (size_t)row * NG + g] = (float)bidx;

    // usage histogram (integer atomics: deterministic)
    atomicAdd(reinterpret_cast<unsigned*>(ws) + WS_HIST + bidx, 1u);

    // block-level commitment partial (deterministic tree)
    for (int off = 32; off > 0; off >>= 1) lsum += __shfl_down(lsum, off);
    __shared__ float sh[4];
    if ((tid & 63) == 0) sh[tid >> 6] = lsum;
    __syncthreads();
    if (tid == 0)
        ws[WS_PART + blockIdx.y * 32 + blockIdx.x] =
            (sh[0] + sh[1]) + (sh[2] + sh[3]);
}

// ---------------- finalize: entropy, perplexity, scalars ----------------
__global__ __launch_bounds__(1024) void vq_final(const float* __restrict__ ws,
                                                 float* out) {
    const int t = threadIdx.x;
    __shared__ float sh[1024];
    const unsigned cnt = reinterpret_cast<const unsigned*>(ws)[WS_HIST + t];
    const float usage  = (float)cnt * (1.0f / 65536.f);
    sh[t] = -usage * logf(usage + 1e-10f);
    __syncthreads();
    for (int s = 512; s > 0; s >>= 1) {
        if (t < s) sh[t] = sh[t] + sh[t + s];
        __syncthreads();
    }
    if (t == 0) {
        const float entropy = sh[0];
        float csum = 0.f;
        for (int i = 0; i < NBLK; ++i) csum += ws[WS_PART + i];
        float* sc = out + (size_t)NB * GD + (size_t)NB * NG;
        sc[0] = csum * (1.0f / ((float)NB * NG * ND));  // commitment_loss
        sc[1] = 0.0f;                                   // codebook_loss
        sc[2] = entropy;
        sc[3] = expf(entropy);                          // perplexity
    }
}

extern "C" void kernel_launch(void* const* d_in, const int* in_sizes, int n_in,
                              void* d_out, int out_size, void* d_ws, size_t ws_size,
                              hipStream_t stream) {
    const float* z  = (const float*)d_in[0];
    const float* cb = (const float*)d_in[1];
    float* out = (float*)d_out;
    float* ws  = (float*)d_ws;

    hipLaunchKernelGGL(vq_c2,    dim3(32),    dim3(256),  0, stream, cb, ws);
    hipLaunchKernelGGL(vq_main,  dim3(32, 8), dim3(256),  0, stream, z, cb, out, ws);
    hipLaunchKernelGGL(vq_final, dim3(1),     dim3(1024), 0, stream, ws, out);
}

// Round 2
// 146.113 us; speedup vs baseline: 1.8598x; 1.8598x over previous
//
#include <hip/hip_runtime.h>
#include <math.h>

#define NB 8192
#define NG 8
#define NK 1024
#define ND 64
#define GD (NG * ND)          // 512
#define KCH (NK / 4)          // 256 codes per wave

// ws float-indexed layout:
// [0, 8192)            c2[g][k]
// [8192, 9216)         histogram (unsigned)
// [9216, 9216+1024)    per-block commitment partials
#define WS_C2   0
#define WS_HIST 8192
#define WS_PART 9216
#define NBLK    1024          // main-kernel block count (128 x 8)

// ---------------- c2 + hist init ----------------
__global__ __launch_bounds__(256) void vq_c2(const float* __restrict__ cb,
                                             float* ws) {
    const int gid = blockIdx.x * 256 + threadIdx.x;   // 0 .. 8191
    const float* c = cb + (size_t)gid * ND;
    float a0 = 0.f, a1 = 0.f, a2 = 0.f, a3 = 0.f;
#pragma unroll
    for (int d = 0; d < ND; d += 4) {
        const float4 v = reinterpret_cast<const float4*>(c)[d >> 2];
        a0 = fmaf(v.x, v.x, a0);
        a1 = fmaf(v.y, v.y, a1);
        a2 = fmaf(v.z, v.z, a2);
        a3 = fmaf(v.w, v.w, a3);
    }
    ws[WS_C2 + gid] = (a0 + a1) + (a2 + a3);
    if (gid < NK) reinterpret_cast<unsigned*>(ws)[WS_HIST + gid] = 0u;
}

// ---------------- main: 64 rows/block, K split across 4 waves ----------------
__global__ __launch_bounds__(256, 4) void vq_main(const float* __restrict__ z,
                                                  const float* __restrict__ cb,
                                                  float* __restrict__ out,
                                                  float* __restrict__ ws) {
    const int tid  = threadIdx.x;
    const int lane = tid & 63;
    // readfirstlane => provably wave-uniform => codebook loads stay s_load
    const int wv   = __builtin_amdgcn_readfirstlane(tid >> 6);   // 0..3
    const int g    = blockIdx.y;
    const int row  = blockIdx.x * 64 + lane;

    // z row segment resident in VGPRs (launch_bounds(256,4) -> 128 VGPR cap)
    const float* zr = z + (size_t)row * GD + (size_t)g * ND;
    float4 zv[16];
#pragma unroll
    for (int i = 0; i < 16; ++i) zv[i] = reinterpret_cast<const float4*>(zr)[i];

    float z2a = 0.f, z2b = 0.f, z2c = 0.f, z2d = 0.f;
#pragma unroll
    for (int i = 0; i < 16; ++i) {
        z2a = fmaf(zv[i].x, zv[i].x, z2a);
        z2b = fmaf(zv[i].y, zv[i].y, z2b);
        z2c = fmaf(zv[i].z, zv[i].z, z2c);
        z2d = fmaf(zv[i].w, zv[i].w, z2d);
    }
    const float z2 = (z2a + z2b) + (z2c + z2d);

    const float* cg  = cb + (size_t)g * NK * ND;     // wave-uniform
    const float* c2g = ws + WS_C2 + g * NK;

    const int k0 = wv * KCH;
    float best = INFINITY;
    int   bidx = k0;
    for (int kk = 0; kk < KCH; ++kk) {
        const int k = k0 + kk;
        const float4* ck = reinterpret_cast<const float4*>(cg + (size_t)k * ND);
        float a0 = 0.f, a1 = 0.f, a2 = 0.f, a3 = 0.f;
#pragma unroll
        for (int i = 0; i < 16; ++i) {
            const float4 c4 = ck[i];                 // wave-uniform -> s_load
            a0 = fmaf(zv[i].x, c4.x, a0);
            a1 = fmaf(zv[i].y, c4.y, a1);
            a2 = fmaf(zv[i].z, c4.z, a2);
            a3 = fmaf(zv[i].w, c4.w, a3);
        }
        const float zc   = (a0 + a1) + (a2 + a3);
        const float dist = (z2 + c2g[k]) - 2.0f * zc;   // ref formula
        if (dist < best) { best = dist; bidx = k; }     // first-min in chunk
    }

    // merge the 4 wave-chunks; ascending wave order + strict < == global first-min
    __shared__ float sdist[4][64];
    __shared__ int   sidx[4][64];
    sdist[wv][lane] = best;
    sidx[wv][lane]  = bidx;
    __syncthreads();

    if (tid < 64) {
        float b  = sdist[0][lane];
        int   bi = sidx[0][lane];
#pragma unroll
        for (int w = 1; w < 4; ++w) {
            const float d  = sdist[w][lane];
            const int   di = sidx[w][lane];
            if (d < b) { b = d; bi = di; }
        }

        // gather zq, write quantized = zg + (zq - zg), accumulate commitment
        const float4* qk = reinterpret_cast<const float4*>(cg + (size_t)bi * ND);
        float* orow = out + (size_t)row * GD + (size_t)g * ND;
        float lsum = 0.f;
#pragma unroll
        for (int i = 0; i < 16; ++i) {
            const float4 q = qk[i];
            const float4 x = zv[i];
            float4 o;
            o.x = x.x + (q.x - x.x);
            o.y = x.y + (q.y - x.y);
            o.z = x.z + (q.z - x.z);
            o.w = x.w + (q.w - x.w);
            reinterpret_cast<float4*>(orow)[i] = o;
            const float d0 = x.x - q.x, d1 = x.y - q.y;
            const float d2 = x.z - q.z, d3 = x.w - q.w;
            lsum += d0 * d0;
            lsum += d1 * d1;
            lsum += d2 * d2;
            lsum += d3 * d3;
        }

        out[(size_t)NB * GD + (size_t)row * NG + g] = (float)bi;
        atomicAdd(reinterpret_cast<unsigned*>(ws) + WS_HIST + bi, 1u);

#pragma unroll
        for (int off = 32; off > 0; off >>= 1) lsum += __shfl_down(lsum, off);
        if (lane == 0)
            ws[WS_PART + blockIdx.y * 128 + blockIdx.x] = lsum;
    }
}

// ---------------- finalize: entropy, perplexity, scalars ----------------
__global__ __launch_bounds__(1024) void vq_final(const float* __restrict__ ws,
                                                 float* out) {
    const int t = threadIdx.x;
    __shared__ float sh_e[1024];
    __shared__ float sh_c[1024];
    const unsigned cnt = reinterpret_cast<const unsigned*>(ws)[WS_HIST + t];
    const float usage  = (float)cnt * (1.0f / 65536.f);
    sh_e[t] = -usage * logf(usage + 1e-10f);
    sh_c[t] = ws[WS_PART + t];
    __syncthreads();
    for (int s = 512; s > 0; s >>= 1) {
        if (t < s) {
            sh_e[t] += sh_e[t + s];
            sh_c[t] += sh_c[t + s];
        }
        __syncthreads();
    }
    if (t == 0) {
        const float entropy = sh_e[0];
        float* sc = out + (size_t)NB * GD + (size_t)NB * NG;
        sc[0] = sh_c[0] * (1.0f / ((float)NB * NG * ND));  // commitment_loss
        sc[1] = 0.0f;                                      // codebook_loss
        sc[2] = entropy;
        sc[3] = expf(entropy);                             // perplexity
    }
}

extern "C" void kernel_launch(void* const* d_in, const int* in_sizes, int n_in,
                              void* d_out, int out_size, void* d_ws, size_t ws_size,
                              hipStream_t stream) {
    const float* z  = (const float*)d_in[0];
    const float* cb = (const float*)d_in[1];
    float* out = (float*)d_out;
    float* ws  = (float*)d_ws;

    hipLaunchKernelGGL(vq_c2,    dim3(32),      dim3(256),  0, stream, cb, ws);
    hipLaunchKernelGGL(vq_main,  dim3(128, 8),  dim3(256),  0, stream, z, cb, out, ws);
    hipLaunchKernelGGL(vq_final, dim3(1),       dim3(1024), 0, stream, ws, out);
}

// Round 3
// 115.852 us; speedup vs baseline: 2.3456x; 1.2612x over previous
//
#include <hip/hip_runtime.h>
#include <hip/hip_bf16.h>
#include <math.h>

#define NB 8192
#define NG 8
#define NK 1024
#define ND 64
#define GD 512
#define MARGIN 2.5e-4f

typedef __attribute__((ext_vector_type(8))) short short8;
typedef __attribute__((ext_vector_type(4))) float f32x4;

// ws BYTE layout
#define WS_C2_OFF    0                      // f32[8192]        32KB
#define WS_CBH_OFF   32768                  // bf16[8*1024*64]  1MB
#define WS_CBL_OFF   (32768 + 1048576)      // bf16[8*1024*64]  1MB
#define WS_CAND_OFF  (32768 + 2097152)      // f32x4[65536]     1MB
#define WS_HIST_OFF  (32768 + 3145728)      // u32[1024]
#define WS_PART_OFF  (32768 + 3149824)      // f32[16384]

__device__ inline void bsplit(float v, short& hs, short& ls) {
    __hip_bfloat16 h = __float2bfloat16(v);
    float hf = __bfloat162float(h);
    __hip_bfloat16 l = __float2bfloat16(v - hf);
    hs = *reinterpret_cast<short*>(&h);
    ls = *reinterpret_cast<short*>(&l);
}

__device__ inline float wredsum(float v) {
#pragma unroll
    for (int st = 1; st < 64; st <<= 1) v += __shfl_xor(v, st);
    return v;
}

// ---------------- prep: c2, bf16 hi/lo codebook, hist zero ----------------
__global__ __launch_bounds__(256) void vq_prep(const float* __restrict__ cb,
                                               float* __restrict__ ws) {
    const int gid = blockIdx.x * 256 + threadIdx.x;            // 0..8191
    const float* c = cb + (size_t)gid * ND;
    ushort* cbh = (ushort*)((char*)ws + WS_CBH_OFF) + (size_t)gid * ND;
    ushort* cbl = (ushort*)((char*)ws + WS_CBL_OFF) + (size_t)gid * ND;

    float a0 = 0.f, a1 = 0.f, a2 = 0.f, a3 = 0.f;
#pragma unroll
    for (int i = 0; i < ND / 4; ++i) {
        const float4 v = reinterpret_cast<const float4*>(c)[i];
        a0 = fmaf(v.x, v.x, a0);
        a1 = fmaf(v.y, v.y, a1);
        a2 = fmaf(v.z, v.z, a2);
        a3 = fmaf(v.w, v.w, a3);
        short h0, l0, h1, l1, h2, l2, h3, l3;
        bsplit(v.x, h0, l0); bsplit(v.y, h1, l1);
        bsplit(v.z, h2, l2); bsplit(v.w, h3, l3);
        ushort4 hv, lv;
        hv.x = (ushort)h0; hv.y = (ushort)h1; hv.z = (ushort)h2; hv.w = (ushort)h3;
        lv.x = (ushort)l0; lv.y = (ushort)l1; lv.z = (ushort)l2; lv.w = (ushort)l3;
        reinterpret_cast<ushort4*>(cbh)[i] = hv;
        reinterpret_cast<ushort4*>(cbl)[i] = lv;
    }
    ((float*)((char*)ws + WS_C2_OFF))[gid] = (a0 + a1) + (a2 + a3);
    if (gid < NK) ((unsigned*)((char*)ws + WS_HIST_OFF))[gid] = 0u;
}

// ---------------- score: MFMA bf16 3-split, best+best2 per row ----------------
__global__ __launch_bounds__(256, 2) void vq_score(const float* __restrict__ z,
                                                   float* __restrict__ ws) {
    const int tid  = threadIdx.x;
    const int w    = tid >> 6;
    const int lane = tid & 63;
    const int lo   = lane & 15, hi = lane >> 4;
    const int g    = blockIdx.y;
    const int rbase = blockIdx.x * 128 + w * 32;

    const ushort* cbh = (const ushort*)((const char*)ws + WS_CBH_OFF) + (size_t)g * NK * ND;
    const ushort* cbl = (const ushort*)((const char*)ws + WS_CBL_OFF) + (size_t)g * NK * ND;
    const float*  c2g = (const float*)((const char*)ws + WS_C2_OFF) + g * NK;

    // A fragments (z rows), split to bf16 hi/lo on the fly.
    // frag elem e <-> k = hi*8 + e within the 32-wide k-step, row = lo (+16*m)
    short8 Ah[2][2], Al[2][2];
#pragma unroll
    for (int m = 0; m < 2; ++m)
#pragma unroll
        for (int ks = 0; ks < 2; ++ks) {
            const float* zp = z + (size_t)(rbase + m * 16 + lo) * GD + g * ND + ks * 32 + hi * 8;
            float vv[8];
            *reinterpret_cast<float4*>(&vv[0]) = reinterpret_cast<const float4*>(zp)[0];
            *reinterpret_cast<float4*>(&vv[4]) = reinterpret_cast<const float4*>(zp)[1];
#pragma unroll
            for (int e = 0; e < 8; ++e) {
                short hs, ls;
                bsplit(vv[e], hs, ls);
                Ah[m][ks][e] = hs;
                Al[m][ks][e] = ls;
            }
        }

    float best[8], b2[8];
    int   bk[8], k2[8];
#pragma unroll
    for (int s = 0; s < 8; ++s) { best[s] = 3.0e38f; b2[s] = 3.0e38f; bk[s] = 0; k2[s] = 0; }

    for (int it = 0; it < 16; ++it) {
        const int kb = it * 64;
        // B fragments: codebook is [code][d] = B^T, same 16B-contiguous pattern
        short8 Bh[2][4], Bl[2][4];
#pragma unroll
        for (int ks = 0; ks < 2; ++ks)
#pragma unroll
            for (int n = 0; n < 4; ++n) {
                const size_t off = (size_t)(kb + n * 16 + lo) * ND + ks * 32 + hi * 8;
                Bh[ks][n] = *reinterpret_cast<const short8*>(cbh + off);
                Bl[ks][n] = *reinterpret_cast<const short8*>(cbl + off);
            }
        float c2v[4];
#pragma unroll
        for (int n = 0; n < 4; ++n) c2v[n] = c2g[kb + n * 16 + lo];

        f32x4 acc[2][4] = {};
#pragma unroll
        for (int ks = 0; ks < 2; ++ks)
#pragma unroll
            for (int n = 0; n < 4; ++n)
#pragma unroll
                for (int m = 0; m < 2; ++m) {
                    acc[m][n] = __builtin_amdgcn_mfma_f32_16x16x32_bf16(Ah[m][ks], Bh[ks][n], acc[m][n], 0, 0, 0);
                    acc[m][n] = __builtin_amdgcn_mfma_f32_16x16x32_bf16(Ah[m][ks], Bl[ks][n], acc[m][n], 0, 0, 0);
                    acc[m][n] = __builtin_amdgcn_mfma_f32_16x16x32_bf16(Al[m][ks], Bh[ks][n], acc[m][n], 0, 0, 0);
                }

        // epilogue: score = c2 - 2*zc  (z2 omitted: constant per row)
#pragma unroll
        for (int n = 0; n < 4; ++n) {
            const int kv = kb + n * 16 + lo;
#pragma unroll
            for (int m = 0; m < 2; ++m)
#pragma unroll
                for (int q = 0; q < 4; ++q) {
                    const float s = fmaf(-2.0f, acc[m][n][q], c2v[n]);
                    const int slot = m * 4 + q;
                    const bool lt  = s < best[slot];
                    const bool lt2 = s < b2[slot];
                    b2[slot]  = lt ? best[slot] : (lt2 ? s : b2[slot]);
                    k2[slot]  = lt ? bk[slot]   : (lt2 ? kv : k2[slot]);
                    best[slot] = lt ? s : best[slot];
                    bk[slot]   = lt ? kv : bk[slot];
                }
        }
    }

    // merge across the 16 lo-lanes (lanes sharing rows differ only in lo bits)
#pragma unroll
    for (int st = 1; st < 16; st <<= 1) {
#pragma unroll
        for (int s = 0; s < 8; ++s) {
            const float ob  = __shfl_xor(best[s], st);
            const int   obk = __shfl_xor(bk[s], st);
            const float ob2 = __shfl_xor(b2[s], st);
            const int   ok2 = __shfl_xor(k2[s], st);
            const bool bet = (ob < best[s]) || (ob == best[s] && obk < bk[s]);
            const float lb  = bet ? best[s] : ob;   // loser's best
            const int   lk  = bet ? bk[s]   : obk;
            const float wb2 = bet ? ob2 : b2[s];    // winner's second
            const int   wk2 = bet ? ok2 : k2[s];
            const bool s2 = (lb < wb2) || (lb == wb2 && lk < wk2);
            b2[s] = s2 ? lb : wb2;
            k2[s] = s2 ? lk : wk2;
            best[s] = bet ? ob : best[s];
            bk[s]   = bet ? obk : bk[s];
        }
    }

    if (lo == 0) {
        f32x4* cand = (f32x4*)((char*)ws + WS_CAND_OFF);
#pragma unroll
        for (int m = 0; m < 2; ++m)
#pragma unroll
            for (int q = 0; q < 4; ++q) {
                const int s = m * 4 + q;
                const int row = rbase + m * 16 + hi * 4 + q;
                f32x4 c;
                c[0] = best[s];
                c[1] = __int_as_float(bk[s]);
                c[2] = b2[s];
                c[3] = __int_as_float(k2[s]);
                cand[(size_t)g * NB + row] = c;
            }
    }
}

// ---------------- pick: rescue near-ties exactly, write outputs ----------------
__global__ __launch_bounds__(256) void vq_pick(const float* __restrict__ z,
                                               const float* __restrict__ cb,
                                               float* __restrict__ out,
                                               float* __restrict__ ws) {
    const int tid = threadIdx.x;
    const int wid = tid >> 6;
    const int lane = tid & 63;
    const int unit = blockIdx.x * 4 + wid;     // 0..65535
    const int row = unit >> 3;
    const int g   = unit & 7;

    const f32x4* cand = (const f32x4*)((const char*)ws + WS_CAND_OFF);
    const f32x4 cd = cand[(size_t)g * NB + row];
    const float bapp = cd[0];
    const int   bk   = __float_as_int(cd[1]);

    const float zd = z[(size_t)row * GD + g * ND + lane];
    int win = bk;

    if (cd[2] - bapp <= MARGIN) {              // wave-uniform rescue branch
        const int kalt = __float_as_int(cd[3]);
        const float* cgrp = cb + (size_t)g * NK * ND;
        const float* c2g  = (const float*)((const char*)ws + WS_C2_OFF) + g * NK;
        const float z2 = wredsum(zd * zd);
        const float c1 = cgrp[(size_t)bk * ND + lane];
        const float d1 = (z2 + c2g[bk]) - 2.0f * wredsum(zd * c1);
        const float c2 = cgrp[(size_t)kalt * ND + lane];
        const float d2 = (z2 + c2g[kalt]) - 2.0f * wredsum(zd * c2);
        if (d2 < d1 || (d2 == d1 && kalt < bk)) win = kalt;
    }

    const float cw = cb[((size_t)g * NK + win) * ND + lane];
    out[(size_t)row * GD + g * ND + lane] = zd + (cw - zd);

    const float e = zd - cw;
    const float cs = wredsum(e * e);

    __shared__ float sh[4];
    if (lane == 0) {
        out[(size_t)NB * GD + (size_t)row * NG + g] = (float)win;
        atomicAdd((unsigned*)((char*)ws + WS_HIST_OFF) + win, 1u);
        sh[wid] = cs;
    }
    __syncthreads();
    if (tid == 0)
        ((float*)((char*)ws + WS_PART_OFF))[blockIdx.x] = (sh[0] + sh[1]) + (sh[2] + sh[3]);
}

// ---------------- finalize ----------------
__global__ __launch_bounds__(1024) void vq_final(const float* __restrict__ ws,
                                                 float* __restrict__ out) {
    const int t = threadIdx.x;
    __shared__ float se[1024];
    __shared__ float sc[1024];
    const unsigned cnt = ((const unsigned*)((const char*)ws + WS_HIST_OFF))[t];
    const float usage = (float)cnt * (1.0f / 65536.f);
    se[t] = -usage * logf(usage + 1e-10f);
    const float* part = (const float*)((const char*)ws + WS_PART_OFF);
    float s = 0.f;
#pragma unroll
    for (int i = 0; i < 16; ++i) s += part[t * 16 + i];
    sc[t] = s;
    __syncthreads();
    for (int st = 512; st > 0; st >>= 1) {
        if (t < st) {
            se[t] += se[t + st];
            sc[t] += sc[t + st];
        }
        __syncthreads();
    }
    if (t == 0) {
        float* scal = out + (size_t)NB * GD + (size_t)NB * NG;
        scal[0] = sc[0] * (1.0f / ((float)NB * NG * ND));  // commitment_loss
        scal[1] = 0.0f;                                    // codebook_loss
        scal[2] = se[0];                                   // entropy
        scal[3] = expf(se[0]);                             // perplexity
    }
}

extern "C" void kernel_launch(void* const* d_in, const int* in_sizes, int n_in,
                              void* d_out, int out_size, void* d_ws, size_t ws_size,
                              hipStream_t stream) {
    const float* z  = (const float*)d_in[0];
    const float* cb = (const float*)d_in[1];
    float* out = (float*)d_out;
    float* ws  = (float*)d_ws;

    hipLaunchKernelGGL(vq_prep,  dim3(32),      dim3(256),  0, stream, cb, ws);
    hipLaunchKernelGGL(vq_score, dim3(64, 8),   dim3(256),  0, stream, z, ws);
    hipLaunchKernelGGL(vq_pick,  dim3(16384),   dim3(256),  0, stream, z, cb, out, ws);
    hipLaunchKernelGGL(vq_final, dim3(1),       dim3(1024), 0, stream, ws, out);
}